// Round 1
// 703.409 us; speedup vs baseline: 1.1265x; 1.1265x over previous
//
#include <hip/hip_runtime.h>
#include <cstdint>

#define M_DIM 16384
#define N_DIM 4096
#define K_DIM 4096

// 256x256 tile, BK=128 int8 (128B rows), 8 waves (2M x 4N), 8-phase schedule.
#define BM 256
#define BN 256
#define BK 128

typedef __attribute__((ext_vector_type(4))) int int32x4;

#define GLLD16(g, l)                                              \
  __builtin_amdgcn_global_load_lds(                               \
      (const __attribute__((address_space(1))) void*)(g),         \
      (__attribute__((address_space(3))) void*)(l), 16, 0, 0)

// ---------------------------------------------------------------------------
// Kernel 1: quantize activations. Lane-contiguous float4 loads (16B/lane
// coalesced per instruction) — math bit-identical to previous version.
// ---------------------------------------------------------------------------
__global__ void quant_x_kernel(const float* __restrict__ x,
                               const float* __restrict__ sp,
                               const int* __restrict__ zpp,
                               int8_t* __restrict__ qx) {
  const float s = sp[0];
  const int zp = zpp[0];
  const size_t b = (size_t)blockIdx.x * 1024;
  const float4* x4 = (const float4*)x;
  unsigned* q4 = (unsigned*)qx;
#pragma unroll
  for (int i = 0; i < 4; i++) {
    const size_t idx = b + (size_t)i * 256 + threadIdx.x;
    float4 v = x4[idx];
    int q0 = min(127, max(-128, (int)rintf(v.x / s) + zp));
    int q1 = min(127, max(-128, (int)rintf(v.y / s) + zp));
    int q2 = min(127, max(-128, (int)rintf(v.z / s) + zp));
    int q3 = min(127, max(-128, (int)rintf(v.w / s) + zp));
    q4[idx] = (unsigned)(q0 & 255) | ((unsigned)(q1 & 255) << 8) |
              ((unsigned)(q2 & 255) << 16) | ((unsigned)(q3 & 255) << 24);
  }
}

// ---------------------------------------------------------------------------
// Kernel 2: quantize weights + wsum -> cs/off. Unchanged.
// ---------------------------------------------------------------------------
__global__ void quant_w_kernel(const float* __restrict__ w,
                               const float* __restrict__ wscale,
                               const float* __restrict__ bias,
                               const float* __restrict__ sp,
                               const int* __restrict__ zpp,
                               int8_t* __restrict__ qw,
                               float* __restrict__ cs,
                               float* __restrict__ off) {
  const int n = blockIdx.x;
  const float ws = wscale[n];
  const float s = sp[0];
  const int zp = zpp[0];
  const float4* wr = (const float4*)(w + (size_t)n * K_DIM);
  unsigned* qr = (unsigned*)(qw + (size_t)n * K_DIM);
  int sum = 0;
#pragma unroll
  for (int it = 0; it < K_DIM / (256 * 4); it++) {
    const int idx = it * 256 + threadIdx.x;
    float4 v = wr[idx];
    int q0 = min(127, max(-128, (int)rintf(v.x / ws)));
    int q1 = min(127, max(-128, (int)rintf(v.y / ws)));
    int q2 = min(127, max(-128, (int)rintf(v.z / ws)));
    int q3 = min(127, max(-128, (int)rintf(v.w / ws)));
    sum += q0 + q1 + q2 + q3;
    qr[idx] = (unsigned)(q0 & 255) | ((unsigned)(q1 & 255) << 8) |
              ((unsigned)(q2 & 255) << 16) | ((unsigned)(q3 & 255) << 24);
  }
  __shared__ int red[4];
#pragma unroll
  for (int o = 32; o > 0; o >>= 1) sum += __shfl_down(sum, o, 64);
  if ((threadIdx.x & 63) == 0) red[threadIdx.x >> 6] = sum;
  __syncthreads();
  if (threadIdx.x == 0) {
    const int tot = red[0] + red[1] + red[2] + red[3];
    const float c = s * ws;
    cs[n] = c;
    off[n] = bias[n] - (float)(zp * tot) * c;
  }
}

// ---------------------------------------------------------------------------
// Kernel 3: int8 GEMM, 256^2 8-phase template (T1+T2+T3+T4+T5).
//
// LDS (128 KB): lds[buf(2)][mat(A,B)][256 rows][128 B], rows PERMUTED so each
// staged 16KB half == exactly the rows one compute phase reads:
//   A lds row r: mhalf=r>>7, wm=(r>>6)&1, sub=r&63 -> tile row wm*128+mhalf*64+sub
//   B lds row r: nhalf=r>>7, wn=(r>>5)&3, sub=r&31 -> tile row wn*64+nhalf*32+sub
// Chunk swizzle (T2): 16B chunk c of row r stored at c ^ (r&7); inverse applied
// to the per-lane GLOBAL source (global_load_lds dest stays linear), same XOR
// applied on ds_read. Fragment read: 16 lanes (fr=0..15) hit 8 chunks x 2 = 2
// lanes/bank = conflict-free.
//
// 8 phases / iter, 2 K-tiles (e=2i in buf0, o=2i+1 in buf1) / iter.
// Stage stream (1 half/phase, 2 glld each): P1:buf1.A.h1<-t(2i+1)  P2:buf0.A.h0
// P3:buf0.B.h0 P4:buf0.B.h1 P5:buf0.A.h1 <- t(2i+2); P6:A.h0 P7:B.h0 P8:B.h1 of
// buf1 <- t(2i+3). Every stage targets a region whose last ds_read drained >=1
// phase earlier (lgkmcnt(0) precedes that phase's end barrier). vmcnt(6) at
// P4/P8 only = 3 halves in flight; forces the tile read next half-iteration
// fully landed.
// ---------------------------------------------------------------------------
__global__ __launch_bounds__(512, 2) void gemm_i8(
    const int8_t* __restrict__ qx, const int8_t* __restrict__ qw,
    const float* __restrict__ cs, const float* __restrict__ off,
    float* __restrict__ out) {
  __shared__ __align__(16) int8_t lds[131072];

  const int tid = threadIdx.x;
  const int lane = tid & 63;
  const int wave = tid >> 6;  // 0..7
  const int wm = wave >> 2;   // 0..1  (128 rows each)
  const int wn = wave & 3;    // 0..3  (64 cols each)

  // T1: XCD-aware swizzle, nwg=1024 (%8==0 -> simple bijective form)
  const int bid = blockIdx.x;
  const int swz = (bid & 7) * 128 + (bid >> 3);
  const int n0 = (swz & 15) * BN;
  const int m0 = (swz >> 4) * BM;

  int32x4 acc[8][4] = {};
  int32x4 af[8], bf0[4], bf1[4];

  // ---- staging source pointers (2 glld per wave per half; lane-linear LDS
  // dest; inverse-swizzled global source) ----
  const int scol = ((lane & 7) ^ ((lane >> 3) & 7)) * 16;
  const int8_t* pA[2][2];
  const int8_t* pB[2][2];
#pragma unroll
  for (int h = 0; h < 2; h++)
#pragma unroll
    for (int j = 0; j < 2; j++) {
      const int r = h * 128 + (wave * 2 + j) * 8 + (lane >> 3);  // lds row
      const int ga = ((r >> 6) & 1) * 128 + (r >> 7) * 64 + (r & 63);
      const int gb = ((r >> 5) & 3) * 64 + (r >> 7) * 32 + (r & 31);
      pA[h][j] = qx + (size_t)(m0 + ga) * K_DIM + scol;
      pB[h][j] = qw + (size_t)(n0 + gb) * K_DIM + scol;
    }

  // ---- fragment read offsets (h=0 / g=0; +16384 per half) ----
  const int fr = lane & 15;
  const int quad = lane >> 4;
  int aoffs[8], boffs[4];
#pragma unroll
  for (int mtl = 0; mtl < 4; mtl++)
#pragma unroll
    for (int ks = 0; ks < 2; ks++) {
      const int r = wm * 64 + mtl * 16 + fr;
      const int c = (ks * 4 + quad) ^ (fr & 7);
      aoffs[mtl * 2 + ks] = r * 128 + c * 16;
    }
#pragma unroll
  for (int ntl = 0; ntl < 2; ntl++)
#pragma unroll
    for (int ks = 0; ks < 2; ks++) {
      const int r = wn * 32 + ntl * 16 + fr;
      const int c = (ks * 4 + quad) ^ (fr & 7);
      boffs[ntl * 2 + ks] = r * 128 + c * 16;
    }

#define STAGE(rbase, h, P, kb)                                          \
  do {                                                                  \
    GLLD16(P[h][0] + (kb), lds + (rbase) + (h) * 16384 + wave * 2048);  \
    GLLD16(P[h][1] + (kb),                                              \
           lds + (rbase) + (h) * 16384 + wave * 2048 + 1024);           \
  } while (0)

#define LDA(buf, h)                                                     \
  do {                                                                  \
    _Pragma("unroll") for (int q = 0; q < 8; q++) af[q] =               \
        *(const int32x4*)(lds + (buf) * 65536 + (h) * 16384 + aoffs[q]); \
  } while (0)

#define LDB(buf, g, BF)                                                 \
  do {                                                                  \
    _Pragma("unroll") for (int q = 0; q < 4; q++) BF[q] =               \
        *(const int32x4*)(lds + (buf) * 65536 + 32768 + (g) * 16384 +   \
                          boffs[q]);                                    \
  } while (0)

#define MM(h, g, BF)                                                       \
  do {                                                                    \
    _Pragma("unroll") for (int mtl = 0; mtl < 4; mtl++)                   \
        _Pragma("unroll") for (int ntl = 0; ntl < 2; ntl++) {             \
      acc[(h)*4 + mtl][(g)*2 + ntl] = __builtin_amdgcn_mfma_i32_16x16x64_i8( \
          af[mtl * 2 + 0], BF[ntl * 2 + 0], acc[(h)*4 + mtl][(g)*2 + ntl], \
          0, 0, 0);                                                        \
      acc[(h)*4 + mtl][(g)*2 + ntl] = __builtin_amdgcn_mfma_i32_16x16x64_i8( \
          af[mtl * 2 + 1], BF[ntl * 2 + 1], acc[(h)*4 + mtl][(g)*2 + ntl], \
          0, 0, 0);                                                        \
    }                                                                      \
  } while (0)

#define BAR() __builtin_amdgcn_s_barrier()
#define WAITLGKM() asm volatile("s_waitcnt lgkmcnt(0)" ::: "memory")
#define VM6() asm volatile("s_waitcnt vmcnt(6)" ::: "memory")
#define PRIO(x) __builtin_amdgcn_s_setprio(x)

  // ---- prologue: tile0 -> buf0 (4 halves), tile1 -> buf1 (3 halves; A.h1
  // comes at P1 of i=0). vmcnt(6): tile0's 8 loads landed, tile1's 6 in flight.
  STAGE(0, 0, pA, 0);
  STAGE(0, 1, pA, 0);
  STAGE(32768, 0, pB, 0);
  STAGE(32768, 1, pB, 0);
  STAGE(65536, 0, pA, 128);
  STAGE(98304, 0, pB, 128);
  STAGE(98304, 1, pB, 128);
  VM6();
  BAR();

  for (int i = 0; i < K_DIM / (2 * BK); i++) {
    const int kb1 = ((2 * i + 1) << 7) & (K_DIM - 1);
    const int kb2 = ((2 * i + 2) << 7) & (K_DIM - 1);
    const int kb3 = ((2 * i + 3) << 7) & (K_DIM - 1);
    // P1: compute e.(h0 x g0); stage buf1.A.h1 <- tile 2i+1
    LDA(0, 0);
    LDB(0, 0, bf0);
    STAGE(65536, 1, pA, kb1);
    BAR(); WAITLGKM(); PRIO(1); MM(0, 0, bf0); PRIO(0); BAR();
    // P2: e.(h0 x g1); stage buf0.A.h0 <- tile 2i+2
    LDB(0, 1, bf1);
    STAGE(0, 0, pA, kb2);
    BAR(); WAITLGKM(); PRIO(1); MM(0, 1, bf1); PRIO(0); BAR();
    // P3: e.(h1 x g1); stage buf0.B.h0
    LDA(0, 1);
    STAGE(32768, 0, pB, kb2);
    BAR(); WAITLGKM(); PRIO(1); MM(1, 1, bf1); PRIO(0); BAR();
    // P4: e.(h1 x g0); stage buf0.B.h1; counted vmcnt -> tile 2i+1 complete
    STAGE(32768, 1, pB, kb2);
    VM6();
    BAR(); PRIO(1); MM(1, 0, bf0); PRIO(0); BAR();
    // P5: o.(h0 x g0); stage buf0.A.h1
    LDA(1, 0);
    LDB(1, 0, bf0);
    STAGE(0, 1, pA, kb2);
    BAR(); WAITLGKM(); PRIO(1); MM(0, 0, bf0); PRIO(0); BAR();
    // P6: o.(h0 x g1); stage buf1.A.h0 <- tile 2i+3
    LDB(1, 1, bf1);
    STAGE(65536, 0, pA, kb3);
    BAR(); WAITLGKM(); PRIO(1); MM(0, 1, bf1); PRIO(0); BAR();
    // P7: o.(h1 x g1); stage buf1.B.h0
    LDA(1, 1);
    STAGE(98304, 0, pB, kb3);
    BAR(); WAITLGKM(); PRIO(1); MM(1, 1, bf1); PRIO(0); BAR();
    // P8: o.(h1 x g0); stage buf1.B.h1; counted vmcnt -> tile 2i+2 complete
    STAGE(98304, 1, pB, kb3);
    VM6();
    BAR(); PRIO(1); MM(1, 0, bf0); PRIO(0); BAR();
  }

  // ---- epilogue: out = acc * cs[col] + off[col] ----
#pragma unroll
  for (int nt = 0; nt < 4; nt++) {
    const int col = n0 + wn * 64 + nt * 16 + fr;
    const float c = cs[col];
    const float o = off[col];
#pragma unroll
    for (int mt = 0; mt < 8; mt++) {
      const int rowb = m0 + wm * 128 + mt * 16 + quad * 4;
#pragma unroll
      for (int r = 0; r < 4; r++) {
        out[(size_t)(rowb + r) * N_DIM + col] = (float)acc[mt][nt][r] * c + o;
      }
    }
  }
#undef STAGE
#undef LDA
#undef LDB
#undef MM
#undef BAR
#undef WAITLGKM
#undef VM6
#undef PRIO
}

// ---------------------------------------------------------------------------
extern "C" void kernel_launch(void* const* d_in, const int* in_sizes, int n_in,
                              void* d_out, int out_size, void* d_ws,
                              size_t ws_size, hipStream_t stream) {
  const float* x = (const float*)d_in[0];
  const float* w = (const float*)d_in[1];
  const float* bias = (const float*)d_in[2];
  const float* act_scale = (const float*)d_in[3];
  const int* zp = (const int*)d_in[4];
  const float* wscale = (const float*)d_in[5];
  float* out = (float*)d_out;

  int8_t* qx = (int8_t*)d_ws;                          // 64 MB
  int8_t* qw = qx + (size_t)M_DIM * K_DIM;             // 16 MB
  float* cs = (float*)(qw + (size_t)N_DIM * K_DIM);    // 16 KB
  float* off = cs + N_DIM;                             // 16 KB

  quant_x_kernel<<<16384, 256, 0, stream>>>(x, act_scale, zp, qx);
  quant_w_kernel<<<N_DIM, 256, 0, stream>>>(w, wscale, bias, act_scale, zp,
                                            qw, cs, off);
  gemm_i8<<<dim3((M_DIM / BM) * (N_DIM / BN)), 512, 0, stream>>>(qx, qw, cs,
                                                                 off, out);
}

// Round 3
// 666.223 us; speedup vs baseline: 1.1894x; 1.0558x over previous
//
#include <hip/hip_runtime.h>
#include <cstdint>

#define M_DIM 16384
#define N_DIM 4096
#define K_DIM 4096

// 256x256 tile, BK=128 int8 (128B rows), 8 waves (2M x 4N), 8-phase schedule.
#define BM 256
#define BN 256
#define BK 128

typedef __attribute__((ext_vector_type(4))) int int32x4;
typedef __attribute__((ext_vector_type(4))) float f32x4;

#define GLLD16(g, l)                                              \
  __builtin_amdgcn_global_load_lds(                               \
      (const __attribute__((address_space(1))) void*)(g),         \
      (__attribute__((address_space(3))) void*)(l), 16, 0, 0)

// ---------------------------------------------------------------------------
// Kernel 1: quantize activations. Lane-contiguous 16B loads; NT loads
// (x is read exactly once — don't pollute L2/L3, keep qx resident instead).
// ---------------------------------------------------------------------------
__global__ void quant_x_kernel(const float* __restrict__ x,
                               const float* __restrict__ sp,
                               const int* __restrict__ zpp,
                               int8_t* __restrict__ qx) {
  const float s = sp[0];
  const int zp = zpp[0];
  const size_t b = (size_t)blockIdx.x * 1024;
  const f32x4* x4 = (const f32x4*)x;
  unsigned* q4 = (unsigned*)qx;
#pragma unroll
  for (int i = 0; i < 4; i++) {
    const size_t idx = b + (size_t)i * 256 + threadIdx.x;
    f32x4 v = __builtin_nontemporal_load(&x4[idx]);
    int q0 = min(127, max(-128, (int)rintf(v[0] / s) + zp));
    int q1 = min(127, max(-128, (int)rintf(v[1] / s) + zp));
    int q2 = min(127, max(-128, (int)rintf(v[2] / s) + zp));
    int q3 = min(127, max(-128, (int)rintf(v[3] / s) + zp));
    q4[idx] = (unsigned)(q0 & 255) | ((unsigned)(q1 & 255) << 8) |
              ((unsigned)(q2 & 255) << 16) | ((unsigned)(q3 & 255) << 24);
  }
}

// ---------------------------------------------------------------------------
// Kernel 2: quantize weights + wsum -> cs/off. NT loads for w (read once).
// ---------------------------------------------------------------------------
__global__ void quant_w_kernel(const float* __restrict__ w,
                               const float* __restrict__ wscale,
                               const float* __restrict__ bias,
                               const float* __restrict__ sp,
                               const int* __restrict__ zpp,
                               int8_t* __restrict__ qw,
                               float* __restrict__ cs,
                               float* __restrict__ off) {
  const int n = blockIdx.x;
  const float ws = wscale[n];
  const float s = sp[0];
  const int zp = zpp[0];
  const f32x4* wr = (const f32x4*)(w + (size_t)n * K_DIM);
  unsigned* qr = (unsigned*)(qw + (size_t)n * K_DIM);
  int sum = 0;
#pragma unroll
  for (int it = 0; it < K_DIM / (256 * 4); it++) {
    const int idx = it * 256 + threadIdx.x;
    f32x4 v = __builtin_nontemporal_load(&wr[idx]);
    int q0 = min(127, max(-128, (int)rintf(v[0] / ws)));
    int q1 = min(127, max(-128, (int)rintf(v[1] / ws)));
    int q2 = min(127, max(-128, (int)rintf(v[2] / ws)));
    int q3 = min(127, max(-128, (int)rintf(v[3] / ws)));
    sum += q0 + q1 + q2 + q3;
    qr[idx] = (unsigned)(q0 & 255) | ((unsigned)(q1 & 255) << 8) |
              ((unsigned)(q2 & 255) << 16) | ((unsigned)(q3 & 255) << 24);
  }
  __shared__ int red[4];
#pragma unroll
  for (int o = 32; o > 0; o >>= 1) sum += __shfl_down(sum, o, 64);
  if ((threadIdx.x & 63) == 0) red[threadIdx.x >> 6] = sum;
  __syncthreads();
  if (threadIdx.x == 0) {
    const int tot = red[0] + red[1] + red[2] + red[3];
    const float c = s * ws;
    cs[n] = c;
    off[n] = bias[n] - (float)(zp * tot) * c;
  }
}

// ---------------------------------------------------------------------------
// Kernel 3: int8 GEMM, 256^2 8-phase template (T1+T2+T3+T4+T5).
//
// LDS (128 KB): lds[buf(2)][mat(A,B)][256 rows][128 B], rows PERMUTED so each
// staged 16KB half == exactly the rows one compute phase reads:
//   A lds row r: mhalf=r>>7, wm=(r>>6)&1, sub=r&63 -> tile row wm*128+mhalf*64+sub
//   B lds row r: nhalf=r>>7, wn=(r>>5)&3, sub=r&31 -> tile row wn*64+nhalf*32+sub
// Chunk swizzle (T2): 16B chunk c of row r stored at c ^ (r&7); inverse applied
// to the per-lane GLOBAL source (global_load_lds dest stays linear), same XOR
// applied on ds_read. Fragment read: 16 lanes (fr=0..15) hit 8 chunks x 2 = 2
// lanes/bank = conflict-free.
//
// 8 phases / iter, 2 K-tiles (e=2i in buf0, o=2i+1 in buf1) / iter.
// Stage stream (1 half/phase, 2 glld each): P1:buf1.A.h1<-t(2i+1)  P2:buf0.A.h0
// P3:buf0.B.h0 P4:buf0.B.h1 P5:buf0.A.h1 <- t(2i+2); P6:A.h0 P7:B.h0 P8:B.h1 of
// buf1 <- t(2i+3). Every stage targets a region whose last ds_read drained >=1
// phase earlier (lgkmcnt(0) precedes that phase's end barrier). vmcnt(6) at
// P4/P8 only = 3 halves in flight.
//
// OPERAND SWAP: mfma(A-op=qw frag, B-op=qx frag) -> D's reg-indexed dim = N
// cols, D's lane dim = M rows. Each lane holds 4 CONSECUTIVE N-columns per
// acc tile -> f32x4 NT epilogue stores (32 dwordx4/thread instead of 128
// scalar dwords; out never re-read -> don't evict qx/qw from L2/L3).
// ---------------------------------------------------------------------------
__global__ __launch_bounds__(512, 2) void gemm_i8(
    const int8_t* __restrict__ qx, const int8_t* __restrict__ qw,
    const float* __restrict__ cs, const float* __restrict__ off,
    float* __restrict__ out) {
  __shared__ __align__(16) int8_t lds[131072];

  const int tid = threadIdx.x;
  const int lane = tid & 63;
  const int wave = tid >> 6;  // 0..7
  const int wm = wave >> 2;   // 0..1  (128 rows each)
  const int wn = wave & 3;    // 0..3  (64 cols each)

  // T1: XCD-aware swizzle, nwg=1024 (%8==0 -> simple bijective form)
  const int bid = blockIdx.x;
  const int swz = (bid & 7) * 128 + (bid >> 3);
  const int n0 = (swz & 15) * BN;
  const int m0 = (swz >> 4) * BM;

  int32x4 acc[8][4] = {};
  int32x4 af[8], bf0[4], bf1[4];

  // ---- staging source pointers (2 glld per wave per half; lane-linear LDS
  // dest; inverse-swizzled global source) ----
  const int scol = ((lane & 7) ^ ((lane >> 3) & 7)) * 16;
  const int8_t* pA[2][2];
  const int8_t* pB[2][2];
#pragma unroll
  for (int h = 0; h < 2; h++)
#pragma unroll
    for (int j = 0; j < 2; j++) {
      const int r = h * 128 + (wave * 2 + j) * 8 + (lane >> 3);  // lds row
      const int ga = ((r >> 6) & 1) * 128 + (r >> 7) * 64 + (r & 63);
      const int gb = ((r >> 5) & 3) * 64 + (r >> 7) * 32 + (r & 31);
      pA[h][j] = qx + (size_t)(m0 + ga) * K_DIM + scol;
      pB[h][j] = qw + (size_t)(n0 + gb) * K_DIM + scol;
    }

  // ---- fragment read offsets (h=0 / g=0; +16384 per half) ----
  const int fr = lane & 15;
  const int quad = lane >> 4;
  int aoffs[8], boffs[4];
#pragma unroll
  for (int mtl = 0; mtl < 4; mtl++)
#pragma unroll
    for (int ks = 0; ks < 2; ks++) {
      const int r = wm * 64 + mtl * 16 + fr;
      const int c = (ks * 4 + quad) ^ (fr & 7);
      aoffs[mtl * 2 + ks] = r * 128 + c * 16;
    }
#pragma unroll
  for (int ntl = 0; ntl < 2; ntl++)
#pragma unroll
    for (int ks = 0; ks < 2; ks++) {
      const int r = wn * 32 + ntl * 16 + fr;
      const int c = (ks * 4 + quad) ^ (fr & 7);
      boffs[ntl * 2 + ks] = r * 128 + c * 16;
    }

#define STAGE(rbase, h, P, kb)                                          \
  do {                                                                  \
    GLLD16(P[h][0] + (kb), lds + (rbase) + (h) * 16384 + wave * 2048);  \
    GLLD16(P[h][1] + (kb),                                              \
           lds + (rbase) + (h) * 16384 + wave * 2048 + 1024);           \
  } while (0)

#define LDA(buf, h)                                                     \
  do {                                                                  \
    _Pragma("unroll") for (int q = 0; q < 8; q++) af[q] =               \
        *(const int32x4*)(lds + (buf) * 65536 + (h) * 16384 + aoffs[q]); \
  } while (0)

#define LDB(buf, g, BF)                                                 \
  do {                                                                  \
    _Pragma("unroll") for (int q = 0; q < 4; q++) BF[q] =               \
        *(const int32x4*)(lds + (buf) * 65536 + 32768 + (g) * 16384 +   \
                          boffs[q]);                                    \
  } while (0)

// Swapped operands: A-operand = qw fragment (lane dim -> D reg dim = N),
// B-operand = qx fragment (lane dim -> D lane dim = M).
#define MM(h, g, BF)                                                       \
  do {                                                                    \
    _Pragma("unroll") for (int mtl = 0; mtl < 4; mtl++)                   \
        _Pragma("unroll") for (int ntl = 0; ntl < 2; ntl++) {             \
      acc[(h)*4 + mtl][(g)*2 + ntl] = __builtin_amdgcn_mfma_i32_16x16x64_i8( \
          BF[ntl * 2 + 0], af[mtl * 2 + 0], acc[(h)*4 + mtl][(g)*2 + ntl], \
          0, 0, 0);                                                        \
      acc[(h)*4 + mtl][(g)*2 + ntl] = __builtin_amdgcn_mfma_i32_16x16x64_i8( \
          BF[ntl * 2 + 1], af[mtl * 2 + 1], acc[(h)*4 + mtl][(g)*2 + ntl], \
          0, 0, 0);                                                        \
    }                                                                      \
  } while (0)

#define BAR() __builtin_amdgcn_s_barrier()
#define WAITLGKM() asm volatile("s_waitcnt lgkmcnt(0)" ::: "memory")
#define VM6() asm volatile("s_waitcnt vmcnt(6)" ::: "memory")
#define PRIO(x) __builtin_amdgcn_s_setprio(x)

  // ---- prologue: tile0 -> buf0 (4 halves), tile1 -> buf1 (3 halves; A.h1
  // comes at P1 of i=0). vmcnt(6): tile0's 8 loads landed, tile1's 6 in flight.
  STAGE(0, 0, pA, 0);
  STAGE(0, 1, pA, 0);
  STAGE(32768, 0, pB, 0);
  STAGE(32768, 1, pB, 0);
  STAGE(65536, 0, pA, 128);
  STAGE(98304, 0, pB, 128);
  STAGE(98304, 1, pB, 128);
  VM6();
  BAR();

  for (int i = 0; i < K_DIM / (2 * BK); i++) {
    const int kb1 = ((2 * i + 1) << 7) & (K_DIM - 1);
    const int kb2 = ((2 * i + 2) << 7) & (K_DIM - 1);
    const int kb3 = ((2 * i + 3) << 7) & (K_DIM - 1);
    // P1: compute e.(h0 x g0); stage buf1.A.h1 <- tile 2i+1
    LDA(0, 0);
    LDB(0, 0, bf0);
    STAGE(65536, 1, pA, kb1);
    BAR(); WAITLGKM(); PRIO(1); MM(0, 0, bf0); PRIO(0); BAR();
    // P2: e.(h0 x g1); stage buf0.A.h0 <- tile 2i+2
    LDB(0, 1, bf1);
    STAGE(0, 0, pA, kb2);
    BAR(); WAITLGKM(); PRIO(1); MM(0, 1, bf1); PRIO(0); BAR();
    // P3: e.(h1 x g1); stage buf0.B.h0
    LDA(0, 1);
    STAGE(32768, 0, pB, kb2);
    BAR(); WAITLGKM(); PRIO(1); MM(1, 1, bf1); PRIO(0); BAR();
    // P4: e.(h1 x g0); stage buf0.B.h1; counted vmcnt -> tile 2i+1 complete
    STAGE(32768, 1, pB, kb2);
    VM6();
    BAR(); PRIO(1); MM(1, 0, bf0); PRIO(0); BAR();
    // P5: o.(h0 x g0); stage buf0.A.h1
    LDA(1, 0);
    LDB(1, 0, bf0);
    STAGE(0, 1, pA, kb2);
    BAR(); WAITLGKM(); PRIO(1); MM(0, 0, bf0); PRIO(0); BAR();
    // P6: o.(h0 x g1); stage buf1.A.h0 <- tile 2i+3
    LDB(1, 1, bf1);
    STAGE(65536, 0, pA, kb3);
    BAR(); WAITLGKM(); PRIO(1); MM(0, 1, bf1); PRIO(0); BAR();
    // P7: o.(h1 x g1); stage buf1.B.h0
    LDA(1, 1);
    STAGE(98304, 0, pB, kb3);
    BAR(); WAITLGKM(); PRIO(1); MM(1, 1, bf1); PRIO(0); BAR();
    // P8: o.(h1 x g0); stage buf1.B.h1; counted vmcnt -> tile 2i+2 complete
    STAGE(98304, 1, pB, kb3);
    VM6();
    BAR(); PRIO(1); MM(1, 0, bf0); PRIO(0); BAR();
  }

  // ---- epilogue: lane holds 4 consecutive N-cols per tile -> f32x4 NT
  // stores. n = colb + reg, m = row-base + fr (lane).
#pragma unroll
  for (int nt = 0; nt < 4; nt++) {
    const int colb = n0 + wn * 64 + nt * 16 + quad * 4;
    const f32x4 c4 = *(const f32x4*)(cs + colb);
    const f32x4 o4 = *(const f32x4*)(off + colb);
#pragma unroll
    for (int mt = 0; mt < 8; mt++) {
      const int row = m0 + wm * 128 + mt * 16 + fr;
      f32x4 v;
      v[0] = (float)acc[mt][nt][0] * c4[0] + o4[0];
      v[1] = (float)acc[mt][nt][1] * c4[1] + o4[1];
      v[2] = (float)acc[mt][nt][2] * c4[2] + o4[2];
      v[3] = (float)acc[mt][nt][3] * c4[3] + o4[3];
      __builtin_nontemporal_store(
          v, (f32x4*)(out + (size_t)row * N_DIM + colb));
    }
  }
#undef STAGE
#undef LDA
#undef LDB
#undef MM
#undef BAR
#undef WAITLGKM
#undef VM6
#undef PRIO
}

// ---------------------------------------------------------------------------
extern "C" void kernel_launch(void* const* d_in, const int* in_sizes, int n_in,
                              void* d_out, int out_size, void* d_ws,
                              size_t ws_size, hipStream_t stream) {
  const float* x = (const float*)d_in[0];
  const float* w = (const float*)d_in[1];
  const float* bias = (const float*)d_in[2];
  const float* act_scale = (const float*)d_in[3];
  const int* zp = (const int*)d_in[4];
  const float* wscale = (const float*)d_in[5];
  float* out = (float*)d_out;

  int8_t* qx = (int8_t*)d_ws;                          // 64 MB
  int8_t* qw = qx + (size_t)M_DIM * K_DIM;             // 16 MB
  float* cs = (float*)(qw + (size_t)N_DIM * K_DIM);    // 16 KB
  float* off = cs + N_DIM;                             // 16 KB

  quant_x_kernel<<<16384, 256, 0, stream>>>(x, act_scale, zp, qx);
  quant_w_kernel<<<N_DIM, 256, 0, stream>>>(w, wscale, bias, act_scale, zp,
                                            qw, cs, off);
  gemm_i8<<<dim3((M_DIM / BM) * (N_DIM / BN)), 512, 0, stream>>>(qx, qw, cs,
                                                                 off, out);
}